// Round 13
// baseline (69.078 us; speedup 1.0000x reference)
//
#include <hip/hip_runtime.h>
#include <hip/hip_bf16.h>
#include <math.h>

#define BSZ   128
#define NP    16
#define NC    21
#define NH    256
#define HOUT  16
#define NFLAT 5376     // K (permuted layout k' = p*336 + c*16 + wo)

// fused-kernel geometry: block (bm, sk): rows 64, K-slice 672 (p = 2sk, 2sk+1)
#define XT_STRIDE 680                      // ushorts; row = 1360 B (16B-mult)
#define XT_BYTES  (64 * XT_STRIDE * 2)     // 87040
#define LDS_TOTAL (XT_BYTES + 4 * 16384)   // + 4 sim tiles = 152576 B
#define PSTR      (2048 * 256)             // part per-sk stride (f32)

typedef __attribute__((ext_vector_type(4))) float f32x4;
typedef __attribute__((ext_vector_type(8))) short bf16x8;

__device__ __forceinline__ ushort f2bf(float v) {
    __hip_bfloat16 h = __float2bfloat16(v);
    return *reinterpret_cast<ushort*>(&h);
}

// tanh(0.01*ln(s)) via odd poly: u in [-0.23, 0.03]; err < 2e-6
__device__ __forceinline__ float hist_act(float s) {
    float u = 0.01f * __logf(fmaxf(s, 1e-10f));
    float u2 = u * u;
    return u * (1.f + u2 * (-0.33333333f + 0.13333333f * u2));
}

// tanh(x) = 1 - 2/(e^{2x}+1)
__device__ __forceinline__ float fast_tanh(float v) {
    float e = __expf(2.f * v);
    return 1.f - 2.f * __builtin_amdgcn_rcpf(e + 1.f);
}

// ---------------------------------------------------------------------------
// Kernel 1 (fused): [blocks 0..167: WtF prep] -> RBF -> gate -> GEMM.
// 256 blocks (bm = bid>>3, sk = bid&7) x 1024 thr (16 waves, 4/SIMD).
// WtF fragment-major: chunk (ks, ntile16, lane) holds Wt elements
//   n = ntile16*16 + (lane&15), k' = ks*32 + (lane>>4)*8 + e   (e = 0..7)
// so one wave B-load = 1KB contiguous.
// xT in LDS with 16B-chunk XOR swizzle: elem k stored at k ^ ((row&7)<<3).
// ---------------------------------------------------------------------------
extern "C" __global__ __launch_bounds__(1024, 1) void k_fused(
    const float* __restrict__ sim,     // [128][16][64][64]
    const float* __restrict__ W,       // [5376][256] fp32
    ushort* __restrict__ WtF,          // fragment-major, 2.75MB
    float* __restrict__ part,          // [8][2048][256]
    uint* __restrict__ cnt)            // [1] zeroed per launch
{
    extern __shared__ __align__(16) char smem[];
    ushort* xT = (ushort*)smem;                       // [64][XT_STRIDE]
    const int bid = blockIdx.x;
    const int bm = bid >> 3, sk = bid & 7;
    const int tid = threadIdx.x;
    const int tg = tid >> 8, tid256 = tid & 255;      // 4 groups of 256

    // ================= PHASE 0: WtF prep (blocks 0..167, ks = bid) ==========
    if (bid < 168) {
        ushort* sW = (ushort*)smem;                   // [32][264] staging
        const int ks = bid;
        int skp = ks / 21, rem = ks - skp * 21;
        int kl = rem * 32;
        int poff = (kl >= 336) ? 1 : 0;
        int p = skp * 2 + poff;
        int cw = kl - poff * 336;
        int c0 = cw >> 4;                             // even
        {
            int r = tid >> 5, ng = tid & 31;          // r: local k (0..31)
            int ksrc = (c0 + (r >> 4)) * 256 + p * 16 + (r & 15);
            const float* wr_ = W + (size_t)ksrc * NH + ng * 8;
            ushort* d = sW + r * 264 + ng * 8;
#pragma unroll
            for (int e = 0; e < 8; ++e) d[e] = f2bf(wr_[e]);
        }
        __syncthreads();
        {
            int nt16 = tid >> 6, l = tid & 63;
            int n = nt16 * 16 + (l & 15);
            int kb = (l >> 4) * 8;
            ushort v[8];
#pragma unroll
            for (int e = 0; e < 8; ++e) v[e] = sW[(kb + e) * 264 + n];
            *(uint4*)(WtF + (((size_t)ks * 16 + nt16) * 64 + l) * 8) = *(uint4*)v;
        }
        __syncthreads();
        if (tid == 0)
            __hip_atomic_fetch_add(cnt, 1u, __ATOMIC_RELEASE, __HIP_MEMORY_SCOPE_AGENT);
        __syncthreads();
    }

    // ================= PHASE A: RBF into LDS xT (2 rounds x 4 tiles) =======
    {
        float* stile = (float*)(smem + XT_BYTES) + tg * 4096;
        int wo = tid256 & 15, ho = tid256 >> 4;

        for (int round = 0; round < 2; ++round) {
            int t8 = round * 4 + tg;                 // 0..7
            int boff = t8 >> 1, poff = t8 & 1;
            const float4* src4 = (const float4*)(sim
                + (((size_t)(4 * bm + boff)) * 16 + (2 * sk + poff)) * 4096);
            float4* s4 = (float4*)stile;
#pragma unroll
            for (int i = 0; i < 4; ++i) s4[i * 256 + tid256] = src4[i * 256 + tid256];
            __syncthreads();

            float f[16], g[16];
            float sum0 = 0.f;
#pragma unroll
            for (int i = 0; i < 4; ++i) {
                float4 e4 = *(const float4*)&stile[(ho * 4 + i) * 64 + wo * 4];
#pragma unroll
                for (int j = 0; j < 4; ++j) {
                    float e = (j == 0) ? e4.x : (j == 1) ? e4.y : (j == 2) ? e4.z : e4.w;
                    int k2 = i * 4 + j;
                    float d0 = e - 1.0f;
                    sum0 += __expf(-50.f * d0 * d0);
                    float d1 = e - 0.95f;
                    f[k2] = __expf(-50.f * d1 * d1);
                    g[k2] = __expf(-10.f * d1 - 0.5f);
                }
            }

            int row = boff * 16 + ho;
            ushort* xrow = xT + row * XT_STRIDE;
            int xmask = (row & 7) << 3;
            int kb = poff * 336 + wo;
            xrow[kb ^ xmask] = f2bf(hist_act(sum0));
#pragma unroll
            for (int c = 1; c < 21; ++c) {
                float sv = 0.f;
#pragma unroll
                for (int k2 = 0; k2 < 16; ++k2) sv += f[k2];
                xrow[(kb + c * 16) ^ xmask] = f2bf(hist_act(sv));
                if (c < 20) {
#pragma unroll
                    for (int k2 = 0; k2 < 16; ++k2) { f[k2] *= g[k2]; g[k2] *= 0.36787944117f; }
                }
            }
            __syncthreads();
        }
    }

    // ================= gate: WtF ready =================
    if (tid == 0) {
        while (__hip_atomic_load(cnt, __ATOMIC_ACQUIRE, __HIP_MEMORY_SCOPE_AGENT) < 168u)
            __builtin_amdgcn_s_sleep(2);
    }
    __syncthreads();

    // ================= PHASE B: GEMM, no barriers, B from global ===========
    {
        int l = tid & 63, w = tid >> 6;
        int wr = w >> 2, wc = w & 3;                // 4x4 waves; wave tile 16 x 64
        int lr = l & 15, lk = l >> 4;
        int arow = wr * 16 + lr;
        int amask = (arow & 7) << 3;
        const char* aBase = (const char*)xT + arow * (XT_STRIDE * 2);

        const ushort* gBF = WtF + (((size_t)sk * 21 * 16 + wc * 4) * 64 + l) * 8;

        f32x4 acc[4];
#pragma unroll
        for (int nt = 0; nt < 4; ++nt) acc[nt] = (f32x4){0.f, 0.f, 0.f, 0.f};

#pragma unroll
        for (int kt = 0; kt < 21; ++kt) {
            int ka = (kt * 32 + lk * 8) ^ amask;
            bf16x8 a = *(const bf16x8*)(aBase + ka * 2);
#pragma unroll
            for (int nt = 0; nt < 4; ++nt) {
                bf16x8 bb = *(const bf16x8*)(gBF + ((size_t)kt * 16 + nt) * 512);
                acc[nt] = __builtin_amdgcn_mfma_f32_16x16x32_bf16(a, bb, acc[nt], 0, 0, 0);
            }
        }

        // store partials: C row=(l>>4)*4+j, col=l&15
        float* pp = part + (size_t)sk * PSTR;
        int crow = bm * 64 + wr * 16 + lk * 4;
#pragma unroll
        for (int nt = 0; nt < 4; ++nt) {
            int ccol = wc * 64 + nt * 16 + lr;
#pragma unroll
            for (int j = 0; j < 4; ++j)
                pp[(size_t)(crow + j) * 256 + ccol] = acc[nt][j];
        }
    }
}

// ---------------------------------------------------------------------------
// Kernel 2: split-K reduce + bias + tanh + attention + heads. 128 x 512 thr.
// ---------------------------------------------------------------------------
__global__ __launch_bounds__(512) void k_head(
    const float* __restrict__ part,    // [8][2048][256]
    const float* __restrict__ b_flat,
    const float* __restrict__ f_add,
    const float* __restrict__ W_attn,
    const float* __restrict__ b_attn,
    const float* __restrict__ W_fadd,
    const float* __restrict__ b_fadd,
    const float* __restrict__ W_d1,
    const float* __restrict__ b_d1,
    const float* __restrict__ W_d2,
    const float* __restrict__ b_d2,
    const float* __restrict__ wfeat,
    float* __restrict__ out)           // [512]
{
    const int b = blockIdx.x;
    const int tid = threadIdx.x;

    __shared__ float sh1[16 * 256];
    __shared__ float slog[16];
    __shared__ float scomb[256];
    __shared__ float scpart[512];
    __shared__ float r01[8];

#pragma unroll
    for (int i = 0; i < 8; ++i) {
        int idx = i * 512 + tid;
        int row = idx >> 8, col = idx & 255;
        size_t prow = (size_t)(b * 16 + row) * 256 + col;
        float v = b_flat[col];
#pragma unroll
        for (int s = 0; s < 8; ++s) v += part[(size_t)s * PSTR + prow];
        sh1[idx] = fast_tanh(v);
    }
    __syncthreads();

    if (tid < 256) {
        int ho = tid >> 4, j = tid & 15;
        float sv = 0.f;
#pragma unroll
        for (int t2 = 0; t2 < 16; ++t2)
            sv += sh1[ho * 256 + j + t2 * 16] * W_attn[j + t2 * 16];
        sv += __shfl_xor(sv, 1); sv += __shfl_xor(sv, 2);
        sv += __shfl_xor(sv, 4); sv += __shfl_xor(sv, 8);
        if (j == 0) slog[ho] = sv + b_attn[0];
    }
    __syncthreads();

    if (tid < 256) {
        float attnv[16];
        float mx = -1e30f;
#pragma unroll
        for (int t2 = 0; t2 < 16; ++t2) mx = fmaxf(mx, slog[t2]);
        float sum = 0.f;
#pragma unroll
        for (int t2 = 0; t2 < 16; ++t2) { attnv[t2] = __expf(slog[t2] - mx); sum += attnv[t2]; }
        float inv = __builtin_amdgcn_rcpf(sum);

        float lc = 0.f;
#pragma unroll
        for (int t2 = 0; t2 < 16; ++t2) lc += attnv[t2] * inv * sh1[t2 * 256 + tid];
        lc = fast_tanh(lc);

        float fp = b_fadd[tid];
#pragma unroll
        for (int k = 0; k < 17; ++k) fp += f_add[b * 17 + k] * W_fadd[k * 256 + tid];
        fp = fast_tanh(fp);

        float sg = __builtin_amdgcn_rcpf(1.f + __expf(-wfeat[0]));
        scomb[tid] = (1.f - sg) * fp + sg * lc;
    }
    __syncthreads();

    {
        int n = tid & 255, half = tid >> 8;
        float sc = 0.f;
        int k0 = half * 128;
#pragma unroll 8
        for (int k = 0; k < 128; ++k) sc += scomb[k0 + k] * W_d1[(k0 + k) * 256 + n];
        scpart[half * 256 + n] = sc;
    }
    __syncthreads();

    if (tid < 256) {
        float sc = fast_tanh(scpart[tid] + scpart[256 + tid] + b_d1[tid]);
        float p0 = sc * W_d2[tid * 2 + 0];
        float p1 = sc * W_d2[tid * 2 + 1];
#pragma unroll
        for (int off = 1; off < 64; off <<= 1) {
            p0 += __shfl_xor(p0, off);
            p1 += __shfl_xor(p1, off);
        }
        if ((tid & 63) == 0) { r01[tid >> 6] = p0; r01[4 + (tid >> 6)] = p1; }
    }
    __syncthreads();

    if (tid == 0) {
        float o0 = r01[0] + r01[1] + r01[2] + r01[3] + b_d2[0];
        float o1 = r01[4] + r01[5] + r01[6] + r01[7] + b_d2[1];
        float mx = fmaxf(o0, o1);
        float lse = mx + __logf(__expf(o0 - mx) + __expf(o1 - mx));
        out[b * 2 + 0] = o0 - lse;
        out[b * 2 + 1] = o1 - lse;
        out[256 + b * 2 + 0] = o0;
        out[256 + b * 2 + 1] = o1;
    }
}

// ---------------------------------------------------------------------------
extern "C" void kernel_launch(void* const* d_in, const int* in_sizes, int n_in,
                              void* d_out, int out_size, void* d_ws, size_t ws_size,
                              hipStream_t stream) {
    const float* sim    = (const float*)d_in[0];
    const float* f_add  = (const float*)d_in[1];
    const float* W_flat = (const float*)d_in[2];
    const float* b_flat = (const float*)d_in[3];
    const float* W_attn = (const float*)d_in[4];
    const float* b_attn = (const float*)d_in[5];
    const float* W_fadd = (const float*)d_in[6];
    const float* b_fadd = (const float*)d_in[7];
    const float* W_d1   = (const float*)d_in[8];
    const float* b_d1   = (const float*)d_in[9];
    const float* W_d2   = (const float*)d_in[10];
    const float* b_d2   = (const float*)d_in[11];
    const float* wfeat  = (const float*)d_in[12];
    float* out = (float*)d_out;

    ushort* WtF = (ushort*)d_ws;                        // 2.75MB fragment-major
    float* part = (float*)(WtF + (size_t)256 * NFLAT);  // [8][2048][256] f32 (16.8MB)
    uint* cnt = (uint*)((char*)d_ws + (36u << 20));     // 1 counter @36MB

    hipMemsetAsync(cnt, 0, sizeof(uint), stream);
    hipLaunchKernelGGL(k_fused, dim3(256), dim3(1024), LDS_TOTAL, stream,
                       sim, W_flat, WtF, part, cnt);
    hipLaunchKernelGGL(k_head, dim3(128), dim3(512), 0, stream,
                       part, b_flat, f_add, W_attn, b_attn, W_fadd, b_fadd,
                       W_d1, b_d1, W_d2, b_d2, wfeat, out);
}

// Round 14
// 55.623 us; speedup vs baseline: 1.2419x; 1.2419x over previous
//
#include <hip/hip_runtime.h>
#include <hip/hip_bf16.h>
#include <math.h>

#define BSZ   128
#define NP    16
#define NC    21
#define NH    256
#define HOUT  16
#define NFLAT 5376     // K (permuted layout k' = p*336 + c*16 + wo)

// fused-kernel geometry: block (bm, sk): rows 64, K-slice 672 (p = 2sk, 2sk+1)
#define XT_STRIDE 680                      // ushorts (672 + 8 pad)
#define XT_BYTES  (64 * XT_STRIDE * 2)     // 87040
#define B_STRIDE  40                       // ushorts per B row (32 + 8 pad)
#define B_BUF     (256 * B_STRIDE * 2)     // 20480 B per buffer
#define LDS_TOTAL (XT_BYTES + 2 * B_BUF)   // 128000 B
#define PSTR      (2048 * 256)             // part per-sk stride (f32)

typedef __attribute__((ext_vector_type(4))) float f32x4;
typedef __attribute__((ext_vector_type(8))) short bf16x8;

__device__ __forceinline__ ushort f2bf(float v) {
    __hip_bfloat16 h = __float2bfloat16(v);
    return *reinterpret_cast<ushort*>(&h);
}

// tanh(0.01*ln(s)) via odd poly: u in [-0.23, 0.03]; err < 2e-6
__device__ __forceinline__ float hist_act(float s) {
    float u = 0.01f * __logf(fmaxf(s, 1e-10f));
    float u2 = u * u;
    return u * (1.f + u2 * (-0.33333333f + 0.13333333f * u2));
}

// tanh(x) = 1 - 2/(e^{2x}+1)
__device__ __forceinline__ float fast_tanh(float v) {
    float e = __expf(2.f * v);
    return 1.f - 2.f * __builtin_amdgcn_rcpf(e + 1.f);
}

// ---------------------------------------------------------------------------
// Kernel 0: Wt[n][k'] = bf16(W_flat[k][n]). 336 blocks x 256 thr (r6-proven).
// ---------------------------------------------------------------------------
__global__ __launch_bounds__(256) void k_prep(const float* __restrict__ W,
                                              ushort* __restrict__ Wt) {
    __shared__ ushort ldsT[64][72];
    int pb = blockIdx.x;
    int kb = pb % 84, nb = pb / 84;
    int k0 = kb * 64, n0 = nb * 64;
    int tid = threadIdx.x;
    int nl = tid & 63, kq = tid >> 6;
#pragma unroll
    for (int i = 0; i < 16; ++i) {
        int kl = i * 4 + kq;
        ldsT[nl][kl] = f2bf(W[(size_t)(k0 + kl) * NH + n0 + nl]);
    }
    __syncthreads();
    int n = tid >> 2, q = tid & 3;
    int k = k0 + q * 16;
    int c = k >> 8, p = (k >> 4) & 15;
    ushort* dst = Wt + (size_t)(n0 + n) * NFLAT + p * 336 + c * 16;
    const ushort* srow = &ldsT[n][q * 16];
#pragma unroll
    for (int i = 0; i < 8; ++i) {
        ushort2 v; v.x = srow[2 * i]; v.y = srow[2 * i + 1];
        ((ushort2*)dst)[i] = v;
    }
}

// ---------------------------------------------------------------------------
// Kernel 1 (fused): RBF (global->reg direct, barrier-free, tree sums)
//                   -> one barrier -> MFMA GEMM (r12 structure).
// 256 blocks (bm = bid>>3, sk = bid&7) x 1024 thr (16 waves, 4/SIMD).
// Wave w, task j: id = j*16+w -> tile t8 = id>>2 (4 boff x 2 poff), quad q=id&3.
// Lane: wo = l&15, ho = q*4 + (l>>4).
// ---------------------------------------------------------------------------
extern "C" __global__ __launch_bounds__(1024, 1) void k_fused(
    const float* __restrict__ sim,     // [128][16][64][64]
    const ushort* __restrict__ Wt,     // [256][5376] bf16
    float* __restrict__ part)          // [8][2048][256]
{
    extern __shared__ __align__(16) char smem[];
    ushort* xT = (ushort*)smem;                       // [64][XT_STRIDE]
    char* Bbase = smem + XT_BYTES;                    // 2 x B_BUF
    const int bid = blockIdx.x;
    const int bm = bid >> 3, sk = bid & 7;
    const int tid = threadIdx.x;

    // ================= PHASE A: RBF, no LDS staging, no barriers ===========
    {
        int w = tid >> 6, l = tid & 63;
        int wo = l & 15, hq = l >> 4;

        float4 ebuf[2][4];
        ushort* xrow_[2];
#pragma unroll
        for (int j = 0; j < 2; ++j) {
            int id = j * 16 + w;
            int t8 = id >> 2, q = id & 3;
            int boff = t8 >> 1, poff = t8 & 1;
            int ho = q * 4 + hq;
            const float* src = sim
                + (((size_t)(4 * bm + boff)) * 16 + (2 * sk + poff)) * 4096
                + (size_t)(ho * 4) * 64 + wo * 4;
#pragma unroll
            for (int i = 0; i < 4; ++i)
                ebuf[j][i] = *(const float4*)(src + i * 64);
            xrow_[j] = xT + (boff * 16 + ho) * XT_STRIDE + poff * 336 + wo;
        }

#pragma unroll
        for (int j = 0; j < 2; ++j) {
            float f[16], g[16];
            float s0[4];
#pragma unroll
            for (int i = 0; i < 4; ++i) {
                float4 e4 = ebuf[j][i];
                float pa = 0.f, pb = 0.f;
#pragma unroll
                for (int jj = 0; jj < 4; ++jj) {
                    float e = (jj == 0) ? e4.x : (jj == 1) ? e4.y : (jj == 2) ? e4.z : e4.w;
                    int k2 = i * 4 + jj;
                    float d0 = e - 1.0f;
                    float t0 = __expf(-50.f * d0 * d0);
                    if (jj & 1) pb += t0; else pa += t0;
                    float d1 = e - 0.95f;
                    f[k2] = __expf(-50.f * d1 * d1);
                    g[k2] = __expf(-10.f * d1 - 0.5f);
                }
                s0[i] = pa + pb;
            }
            float sum0 = (s0[0] + s0[1]) + (s0[2] + s0[3]);
            ushort* xrow = xrow_[j];
            xrow[0] = f2bf(hist_act(sum0));

#pragma unroll
            for (int c = 1; c < 21; ++c) {
                // tree reduction, depth 4
                float t01 = f[0] + f[1],  t23 = f[2] + f[3];
                float t45 = f[4] + f[5],  t67 = f[6] + f[7];
                float t89 = f[8] + f[9],  tab = f[10] + f[11];
                float tcd = f[12] + f[13], tef = f[14] + f[15];
                float u0 = t01 + t23, u1 = t45 + t67;
                float u2 = t89 + tab, u3 = tcd + tef;
                float sv = (u0 + u1) + (u2 + u3);
                xrow[c * 16] = f2bf(hist_act(sv));
                if (c < 20) {
#pragma unroll
                    for (int k2 = 0; k2 < 16; ++k2) { f[k2] *= g[k2]; g[k2] *= 0.36787944117f; }
                }
            }
        }
    }
    __syncthreads();   // xT complete

    // ================= PHASE B: GEMM (21 iters of BK=32, r12 structure) ====
    {
        int l = tid & 63, w = tid >> 6;
        int wr = w >> 2, wc = w & 3;                // 4x4 waves; wave tile 16 x 64
        int lr = l & 15, lk = l >> 4;
        int arow = wr * 16 + lr;

        int brow = tid >> 2, bq = tid & 3;
        const ushort* gB = Wt + (size_t)brow * NFLAT + sk * 672 + bq * 8;
        char* wB0 = Bbase + brow * (B_STRIDE * 2) + bq * 16;
        char* wB1 = wB0 + B_BUF;

        f32x4 acc[4];
#pragma unroll
        for (int nt = 0; nt < 4; ++nt) acc[nt] = (f32x4){0.f, 0.f, 0.f, 0.f};

        uint4 bE = *(const uint4*)(gB);
        uint4 bO = *(const uint4*)(gB + 32);

#define COMPUTE(BUFOFF, IT)                                                      \
        {                                                                        \
            bf16x8 a = *(const bf16x8*)((const char*)xT + arow * (XT_STRIDE*2)   \
                                        + (IT) * 64 + lk * 16);                  \
            _Pragma("unroll")                                                    \
            for (int nt = 0; nt < 4; ++nt) {                                     \
                bf16x8 bb = *(const bf16x8*)(Bbase + (BUFOFF)                    \
                            + (wc * 64 + nt * 16 + lr) * (B_STRIDE*2)            \
                            + lk * 16);                                          \
                acc[nt] = __builtin_amdgcn_mfma_f32_16x16x32_bf16(a, bb, acc[nt], 0, 0, 0); \
            }                                                                    \
        }

#pragma unroll 1
        for (int m = 0; m < 10; ++m) {
            int it = 2 * m;
            __syncthreads();                       // buf0 consumers (it-2) done
            *(uint4*)(wB0) = bE;
            bE = *(const uint4*)(gB + (it + 2) * 32);
            __syncthreads();                       // buf0 ready
            COMPUTE(0, it);

            __syncthreads();                       // buf1 consumers done
            *(uint4*)(wB1) = bO;
            if (m < 9) bO = *(const uint4*)(gB + (it + 3) * 32);
            __syncthreads();
            COMPUTE(B_BUF, it + 1);
        }
        __syncthreads();
        *(uint4*)(wB0) = bE;                       // it = 20
        __syncthreads();
        COMPUTE(0, 20);
#undef COMPUTE

        float* pp = part + (size_t)sk * PSTR;
        int crow = bm * 64 + wr * 16 + lk * 4;
#pragma unroll
        for (int nt = 0; nt < 4; ++nt) {
            int ccol = wc * 64 + nt * 16 + lr;
#pragma unroll
            for (int j = 0; j < 4; ++j)
                pp[(size_t)(crow + j) * 256 + ccol] = acc[nt][j];
        }
    }
}

// ---------------------------------------------------------------------------
// Kernel 2: split-K reduce + bias + tanh + attention + heads. 128 x 512 thr.
// ---------------------------------------------------------------------------
__global__ __launch_bounds__(512) void k_head(
    const float* __restrict__ part,    // [8][2048][256]
    const float* __restrict__ b_flat,
    const float* __restrict__ f_add,
    const float* __restrict__ W_attn,
    const float* __restrict__ b_attn,
    const float* __restrict__ W_fadd,
    const float* __restrict__ b_fadd,
    const float* __restrict__ W_d1,
    const float* __restrict__ b_d1,
    const float* __restrict__ W_d2,
    const float* __restrict__ b_d2,
    const float* __restrict__ wfeat,
    float* __restrict__ out)           // [512]
{
    const int b = blockIdx.x;
    const int tid = threadIdx.x;

    __shared__ float sh1[16 * 256];
    __shared__ float slog[16];
    __shared__ float scomb[256];
    __shared__ float scpart[512];
    __shared__ float r01[8];

#pragma unroll
    for (int i = 0; i < 8; ++i) {
        int idx = i * 512 + tid;
        int row = idx >> 8, col = idx & 255;
        size_t prow = (size_t)(b * 16 + row) * 256 + col;
        float v = b_flat[col];
#pragma unroll
        for (int s = 0; s < 8; ++s) v += part[(size_t)s * PSTR + prow];
        sh1[idx] = fast_tanh(v);
    }
    __syncthreads();

    if (tid < 256) {
        int ho = tid >> 4, j = tid & 15;
        float sv = 0.f;
#pragma unroll
        for (int t2 = 0; t2 < 16; ++t2)
            sv += sh1[ho * 256 + j + t2 * 16] * W_attn[j + t2 * 16];
        sv += __shfl_xor(sv, 1); sv += __shfl_xor(sv, 2);
        sv += __shfl_xor(sv, 4); sv += __shfl_xor(sv, 8);
        if (j == 0) slog[ho] = sv + b_attn[0];
    }
    __syncthreads();

    if (tid < 256) {
        float attnv[16];
        float mx = -1e30f;
#pragma unroll
        for (int t2 = 0; t2 < 16; ++t2) mx = fmaxf(mx, slog[t2]);
        float sum = 0.f;
#pragma unroll
        for (int t2 = 0; t2 < 16; ++t2) { attnv[t2] = __expf(slog[t2] - mx); sum += attnv[t2]; }
        float inv = __builtin_amdgcn_rcpf(sum);

        float lc = 0.f;
#pragma unroll
        for (int t2 = 0; t2 < 16; ++t2) lc += attnv[t2] * inv * sh1[t2 * 256 + tid];
        lc = fast_tanh(lc);

        float fp = b_fadd[tid];
#pragma unroll
        for (int k = 0; k < 17; ++k) fp += f_add[b * 17 + k] * W_fadd[k * 256 + tid];
        fp = fast_tanh(fp);

        float sg = __builtin_amdgcn_rcpf(1.f + __expf(-wfeat[0]));
        scomb[tid] = (1.f - sg) * fp + sg * lc;
    }
    __syncthreads();

    {
        int n = tid & 255, half = tid >> 8;
        float sc = 0.f;
        int k0 = half * 128;
#pragma unroll 8
        for (int k = 0; k < 128; ++k) sc += scomb[k0 + k] * W_d1[(k0 + k) * 256 + n];
        scpart[half * 256 + n] = sc;
    }
    __syncthreads();

    if (tid < 256) {
        float sc = fast_tanh(scpart[tid] + scpart[256 + tid] + b_d1[tid]);
        float p0 = sc * W_d2[tid * 2 + 0];
        float p1 = sc * W_d2[tid * 2 + 1];
#pragma unroll
        for (int off = 1; off < 64; off <<= 1) {
            p0 += __shfl_xor(p0, off);
            p1 += __shfl_xor(p1, off);
        }
        if ((tid & 63) == 0) { r01[tid >> 6] = p0; r01[4 + (tid >> 6)] = p1; }
    }
    __syncthreads();

    if (tid == 0) {
        float o0 = r01[0] + r01[1] + r01[2] + r01[3] + b_d2[0];
        float o1 = r01[4] + r01[5] + r01[6] + r01[7] + b_d2[1];
        float mx = fmaxf(o0, o1);
        float lse = mx + __logf(__expf(o0 - mx) + __expf(o1 - mx));
        out[b * 2 + 0] = o0 - lse;
        out[b * 2 + 1] = o1 - lse;
        out[256 + b * 2 + 0] = o0;
        out[256 + b * 2 + 1] = o1;
    }
}

// ---------------------------------------------------------------------------
extern "C" void kernel_launch(void* const* d_in, const int* in_sizes, int n_in,
                              void* d_out, int out_size, void* d_ws, size_t ws_size,
                              hipStream_t stream) {
    const float* sim    = (const float*)d_in[0];
    const float* f_add  = (const float*)d_in[1];
    const float* W_flat = (const float*)d_in[2];
    const float* b_flat = (const float*)d_in[3];
    const float* W_attn = (const float*)d_in[4];
    const float* b_attn = (const float*)d_in[5];
    const float* W_fadd = (const float*)d_in[6];
    const float* b_fadd = (const float*)d_in[7];
    const float* W_d1   = (const float*)d_in[8];
    const float* b_d1   = (const float*)d_in[9];
    const float* W_d2   = (const float*)d_in[10];
    const float* b_d2   = (const float*)d_in[11];
    const float* wfeat  = (const float*)d_in[12];
    float* out = (float*)d_out;

    ushort* Wt  = (ushort*)d_ws;                        // [256][5376] bf16 (2.75MB)
    float* part = (float*)(Wt + (size_t)256 * NFLAT);   // [8][2048][256] f32 (16.8MB)

    hipLaunchKernelGGL(k_prep, dim3(336), dim3(256), 0, stream, W_flat, Wt);
    hipLaunchKernelGGL(k_fused, dim3(256), dim3(1024), LDS_TOTAL, stream, sim, Wt, part);
    hipLaunchKernelGGL(k_head, dim3(128), dim3(512), 0, stream,
                       part, b_flat, f_add, W_attn, b_attn, W_fadd, b_fadd,
                       W_d1, b_d1, W_d2, b_d2, wfeat, out);
}

// Round 15
// 51.395 us; speedup vs baseline: 1.3441x; 1.0823x over previous
//
#include <hip/hip_runtime.h>
#include <hip/hip_bf16.h>
#include <math.h>

#define BSZ   128
#define NP    16
#define NC    21
#define NH    256
#define HOUT  16
#define NFLAT 5376     // K (permuted layout k' = p*336 + c*16 + wo)

// fused-kernel geometry: block (bm, sk): 32 rows (b = 2bm,2bm+1), K-slice 672
#define XT_STRIDE 680                      // ushorts (672 + 8 pad)
#define XT_BYTES  (32 * XT_STRIDE * 2)     // 43520 -> 2 blocks/CU
#define PSTR      (2048 * 256)             // part per-sk stride (f32)

typedef __attribute__((ext_vector_type(4))) float f32x4;
typedef __attribute__((ext_vector_type(8))) short bf16x8;

__device__ __forceinline__ ushort f2bf(float v) {
    __hip_bfloat16 h = __float2bfloat16(v);
    return *reinterpret_cast<ushort*>(&h);
}

// tanh(0.01*ln(s)) via odd poly: u in [-0.23, 0.03]; err < 2e-6
__device__ __forceinline__ float hist_act(float s) {
    float u = 0.01f * __logf(fmaxf(s, 1e-10f));
    float u2 = u * u;
    return u * (1.f + u2 * (-0.33333333f + 0.13333333f * u2));
}

// tanh(x) = 1 - 2/(e^{2x}+1)
__device__ __forceinline__ float fast_tanh(float v) {
    float e = __expf(2.f * v);
    return 1.f - 2.f * __builtin_amdgcn_rcpf(e + 1.f);
}

// ---------------------------------------------------------------------------
// Kernel 0: WtF fragment-major B. chunk id = (ks*16 + nt16)*64 + lane covers
//   n = nt16*16 + (l&15), k' = ks*32 + (l>>4)*8 + e  (e=0..7, 16B per lane).
// Per-ELEMENT p/c decode (fixes r13 straddle bug). 672 blocks x 256 thr.
// ---------------------------------------------------------------------------
__global__ __launch_bounds__(256) void k_prep(const float* __restrict__ W,
                                              ushort* __restrict__ WtF) {
    int id = blockIdx.x * 256 + threadIdx.x;   // [0, 172032)
    int l = id & 63;
    int ks = id >> 10;                         // [0, 168)
    int n = (((id >> 6) & 15) << 4) + (l & 15);
    int kb = ks * 32 + (l >> 4) * 8;
    ushort v[8];
#pragma unroll
    for (int e = 0; e < 8; ++e) {
        int kp = kb + e;                       // k' in [0, 5376)
        int p = kp / 336;
        int rem = kp - p * 336;
        int c = rem >> 4, wo = rem & 15;
        int ksrc = c * 256 + p * 16 + wo;      // original W row
        v[e] = f2bf(W[(size_t)ksrc * NH + n]);
    }
    *(uint4*)(WtF + (size_t)id * 8) = *(uint4*)v;
}

// ---------------------------------------------------------------------------
// Kernel 1 (fused): RBF (1 task/thread, barrier-free, tree sums) -> 1 barrier
//                   -> GEMM (A from LDS xT, B direct from global WtF, 0 barriers).
// 512 blocks (bm = bid>>3 in [0,64), sk = bid&7) x 1024 thr, 43.5 KB LDS,
// 2 blocks/CU, 8 waves/SIMD.
// ---------------------------------------------------------------------------
extern "C" __global__ __launch_bounds__(1024, 8) void k_fused(
    const float* __restrict__ sim,     // [128][16][64][64]
    const ushort* __restrict__ WtF,    // fragment-major
    float* __restrict__ part)          // [8][2048][256]
{
    extern __shared__ __align__(16) char smem[];
    ushort* xT = (ushort*)smem;                       // [32][XT_STRIDE]
    const int bid = blockIdx.x;
    const int bm = bid >> 3, sk = bid & 7;
    const int tid = threadIdx.x;

    // ================= PHASE A: RBF (1 task/thread) ========================
    {
        int w = tid >> 6, l = tid & 63;
        int tile = w >> 2, q = w & 3;                // 4 sim tiles, ho-quad q
        int boff = tile >> 1, poff = tile & 1;
        int wo = l & 15, ho = q * 4 + (l >> 4);

        const float* src = sim
            + (((size_t)(2 * bm + boff)) * 16 + (2 * sk + poff)) * 4096
            + (size_t)(ho * 4) * 64 + wo * 4;
        float4 ebuf[4];
#pragma unroll
        for (int i = 0; i < 4; ++i) ebuf[i] = *(const float4*)(src + i * 64);

        float f[16], g[16];
        float s0[4];
#pragma unroll
        for (int i = 0; i < 4; ++i) {
            float4 e4 = ebuf[i];
            float pa = 0.f, pb = 0.f;
#pragma unroll
            for (int jj = 0; jj < 4; ++jj) {
                float e = (jj == 0) ? e4.x : (jj == 1) ? e4.y : (jj == 2) ? e4.z : e4.w;
                int k2 = i * 4 + jj;
                float d0 = e - 1.0f;
                float t0 = __expf(-50.f * d0 * d0);
                if (jj & 1) pb += t0; else pa += t0;
                float d1 = e - 0.95f;
                f[k2] = __expf(-50.f * d1 * d1);
                g[k2] = __expf(-10.f * d1 - 0.5f);
            }
            s0[i] = pa + pb;
        }
        float sum0 = (s0[0] + s0[1]) + (s0[2] + s0[3]);
        ushort* xrow = xT + (boff * 16 + ho) * XT_STRIDE + poff * 336 + wo;
        xrow[0] = f2bf(hist_act(sum0));

#pragma unroll
        for (int c = 1; c < 21; ++c) {
            float t01 = f[0] + f[1],  t23 = f[2] + f[3];
            float t45 = f[4] + f[5],  t67 = f[6] + f[7];
            float t89 = f[8] + f[9],  tab = f[10] + f[11];
            float tcd = f[12] + f[13], tef = f[14] + f[15];
            float u0 = t01 + t23, u1 = t45 + t67;
            float u2 = t89 + tab, u3 = tcd + tef;
            float sv = (u0 + u1) + (u2 + u3);
            xrow[c * 16] = f2bf(hist_act(sv));
            if (c < 20) {
#pragma unroll
                for (int k2 = 0; k2 < 16; ++k2) { f[k2] *= g[k2]; g[k2] *= 0.36787944117f; }
            }
        }
    }
    __syncthreads();   // xT complete

    // ================= PHASE B: GEMM (A: LDS, B: global; no barriers) ======
    {
        int l = tid & 63, w = tid >> 6;
        int wr = w >> 3, wc = w & 7;                // 2x8 waves; wave tile 16x32
        int lr = l & 15, lk = l >> 4;
        int arow = wr * 16 + lr;
        const char* aBase = (const char*)xT + arow * (XT_STRIDE * 2);

        // B fragment base: nt16 = wc*2 + nt
        const ushort* gB = WtF + (((size_t)(sk * 21) * 16 + wc * 2) * 64 + l) * 8;

        f32x4 acc[2];
        acc[0] = (f32x4){0.f, 0.f, 0.f, 0.f};
        acc[1] = (f32x4){0.f, 0.f, 0.f, 0.f};

#pragma unroll
        for (int kt = 0; kt < 21; ++kt) {
            bf16x8 a = *(const bf16x8*)(aBase + kt * 64 + lk * 16);
#pragma unroll
            for (int nt = 0; nt < 2; ++nt) {
                bf16x8 bb = *(const bf16x8*)(gB + ((size_t)kt * 16 + nt) * 512);
                acc[nt] = __builtin_amdgcn_mfma_f32_16x16x32_bf16(a, bb, acc[nt], 0, 0, 0);
            }
        }

        // store partials: C row=(l>>4)*4+j, col=l&15
        float* pp = part + (size_t)sk * PSTR;
        int crow = bm * 32 + wr * 16 + lk * 4;
#pragma unroll
        for (int nt = 0; nt < 2; ++nt) {
            int ccol = wc * 32 + nt * 16 + lr;
#pragma unroll
            for (int j = 0; j < 4; ++j)
                pp[(size_t)(crow + j) * 256 + ccol] = acc[nt][j];
        }
    }
}

// ---------------------------------------------------------------------------
// Kernel 2: split-K reduce + bias + tanh + attention + heads. 128 x 512 thr.
// ---------------------------------------------------------------------------
__global__ __launch_bounds__(512) void k_head(
    const float* __restrict__ part,    // [8][2048][256]
    const float* __restrict__ b_flat,
    const float* __restrict__ f_add,
    const float* __restrict__ W_attn,
    const float* __restrict__ b_attn,
    const float* __restrict__ W_fadd,
    const float* __restrict__ b_fadd,
    const float* __restrict__ W_d1,
    const float* __restrict__ b_d1,
    const float* __restrict__ W_d2,
    const float* __restrict__ b_d2,
    const float* __restrict__ wfeat,
    float* __restrict__ out)           // [512]
{
    const int b = blockIdx.x;
    const int tid = threadIdx.x;

    __shared__ float sh1[16 * 256];
    __shared__ float slog[16];
    __shared__ float scomb[256];
    __shared__ float scpart[512];
    __shared__ float r01[8];

#pragma unroll
    for (int i = 0; i < 8; ++i) {
        int idx = i * 512 + tid;
        int row = idx >> 8, col = idx & 255;
        size_t prow = (size_t)(b * 16 + row) * 256 + col;
        float v = b_flat[col];
#pragma unroll
        for (int s = 0; s < 8; ++s) v += part[(size_t)s * PSTR + prow];
        sh1[idx] = fast_tanh(v);
    }
    __syncthreads();

    if (tid < 256) {
        int ho = tid >> 4, j = tid & 15;
        float sv = 0.f;
#pragma unroll
        for (int t2 = 0; t2 < 16; ++t2)
            sv += sh1[ho * 256 + j + t2 * 16] * W_attn[j + t2 * 16];
        sv += __shfl_xor(sv, 1); sv += __shfl_xor(sv, 2);
        sv += __shfl_xor(sv, 4); sv += __shfl_xor(sv, 8);
        if (j == 0) slog[ho] = sv + b_attn[0];
    }
    __syncthreads();

    if (tid < 256) {
        float attnv[16];
        float mx = -1e30f;
#pragma unroll
        for (int t2 = 0; t2 < 16; ++t2) mx = fmaxf(mx, slog[t2]);
        float sum = 0.f;
#pragma unroll
        for (int t2 = 0; t2 < 16; ++t2) { attnv[t2] = __expf(slog[t2] - mx); sum += attnv[t2]; }
        float inv = __builtin_amdgcn_rcpf(sum);

        float lc = 0.f;
#pragma unroll
        for (int t2 = 0; t2 < 16; ++t2) lc += attnv[t2] * inv * sh1[t2 * 256 + tid];
        lc = fast_tanh(lc);

        float fp = b_fadd[tid];
#pragma unroll
        for (int k = 0; k < 17; ++k) fp += f_add[b * 17 + k] * W_fadd[k * 256 + tid];
        fp = fast_tanh(fp);

        float sg = __builtin_amdgcn_rcpf(1.f + __expf(-wfeat[0]));
        scomb[tid] = (1.f - sg) * fp + sg * lc;
    }
    __syncthreads();

    {
        int n = tid & 255, half = tid >> 8;
        float sc = 0.f;
        int k0 = half * 128;
#pragma unroll 8
        for (int k = 0; k < 128; ++k) sc += scomb[k0 + k] * W_d1[(k0 + k) * 256 + n];
        scpart[half * 256 + n] = sc;
    }
    __syncthreads();

    if (tid < 256) {
        float sc = fast_tanh(scpart[tid] + scpart[256 + tid] + b_d1[tid]);
        float p0 = sc * W_d2[tid * 2 + 0];
        float p1 = sc * W_d2[tid * 2 + 1];
#pragma unroll
        for (int off = 1; off < 64; off <<= 1) {
            p0 += __shfl_xor(p0, off);
            p1 += __shfl_xor(p1, off);
        }
        if ((tid & 63) == 0) { r01[tid >> 6] = p0; r01[4 + (tid >> 6)] = p1; }
    }
    __syncthreads();

    if (tid == 0) {
        float o0 = r01[0] + r01[1] + r01[2] + r01[3] + b_d2[0];
        float o1 = r01[4] + r01[5] + r01[6] + r01[7] + b_d2[1];
        float mx = fmaxf(o0, o1);
        float lse = mx + __logf(__expf(o0 - mx) + __expf(o1 - mx));
        out[b * 2 + 0] = o0 - lse;
        out[b * 2 + 1] = o1 - lse;
        out[256 + b * 2 + 0] = o0;
        out[256 + b * 2 + 1] = o1;
    }
}

// ---------------------------------------------------------------------------
extern "C" void kernel_launch(void* const* d_in, const int* in_sizes, int n_in,
                              void* d_out, int out_size, void* d_ws, size_t ws_size,
                              hipStream_t stream) {
    const float* sim    = (const float*)d_in[0];
    const float* f_add  = (const float*)d_in[1];
    const float* W_flat = (const float*)d_in[2];
    const float* b_flat = (const float*)d_in[3];
    const float* W_attn = (const float*)d_in[4];
    const float* b_attn = (const float*)d_in[5];
    const float* W_fadd = (const float*)d_in[6];
    const float* b_fadd = (const float*)d_in[7];
    const float* W_d1   = (const float*)d_in[8];
    const float* b_d1   = (const float*)d_in[9];
    const float* W_d2   = (const float*)d_in[10];
    const float* b_d2   = (const float*)d_in[11];
    const float* wfeat  = (const float*)d_in[12];
    float* out = (float*)d_out;

    ushort* WtF = (ushort*)d_ws;                        // 2.75MB fragment-major
    float* part = (float*)(WtF + (size_t)256 * NFLAT);  // [8][2048][256] f32 (16.8MB)

    hipLaunchKernelGGL(k_prep, dim3(672), dim3(256), 0, stream, W_flat, WtF);
    hipLaunchKernelGGL(k_fused, dim3(512), dim3(1024), XT_BYTES, stream, sim, WtF, part);
    hipLaunchKernelGGL(k_head, dim3(128), dim3(512), 0, stream,
                       part, b_flat, f_add, W_attn, b_attn, W_fadd, b_fadd,
                       W_d1, b_d1, W_d2, b_d2, wfeat, out);
}